// Round 1
// baseline (5797.150 us; speedup 1.0000x reference)
//
#include <hip/hip_runtime.h>
#include <hip/hip_fp16.h>

// ReviewAnalyzeModel: 2-layer biLSTM, B=64 T=512 E=256 H=256, V=50000.
// Phases: prep(cvt fp16) -> GEMM proj0 -> scan0 -> GEMM proj1 -> scan1 -> final linear.

typedef _Float16 f16;
typedef _Float16 half8 __attribute__((ext_vector_type(8)));
typedef float floatx4 __attribute__((ext_vector_type(4)));

#if __has_builtin(__builtin_amdgcn_global_load_lds)
#define HAS_GLL 1
#endif

#if __has_builtin(__builtin_amdgcn_exp2f)
#define EXP2F __builtin_amdgcn_exp2f
#else
#define EXP2F exp2f
#endif
#if __has_builtin(__builtin_amdgcn_rcpf)
#define RCPF __builtin_amdgcn_rcpf
#else
#define RCPF(x) (1.0f/(x))
#endif

__device__ __forceinline__ float sigf(float x) {
  return RCPF(1.f + EXP2F(-1.4426950408889634f * x));
}
__device__ __forceinline__ float tanhf_(float x) {
  return 2.f * RCPF(1.f + EXP2F(-2.8853900817779268f * x)) - 1.f;
}

// ---------------- prep kernels ----------------

__global__ void k_cvt_embed(const float* __restrict__ src, f16* __restrict__ dst, int n8) {
  int i = blockIdx.x * blockDim.x + threadIdx.x;
  if (i >= n8) return;
  const float4* s = (const float4*)(src + (size_t)i * 8);
  float4 a = s[0], b = s[1];
  half8 h = { (f16)a.x,(f16)a.y,(f16)a.z,(f16)a.w,(f16)b.x,(f16)b.y,(f16)b.z,(f16)b.w };
  *(half8*)(dst + (size_t)i * 8) = h;
}

// dst[n'][k], n' = d*1024 + j*4 + gate ; src row (gate*256+j) of Wih_l?_{f,b}
__global__ void k_cvt_wih(const float* __restrict__ sf, const float* __restrict__ sb,
                          f16* __restrict__ dst, int K, int logK, int total) {
  int i = blockIdx.x * blockDim.x + threadIdx.x;
  if (i >= total) return;
  int k = i & (K - 1);
  int n = i >> logK;
  int d = n >> 10;
  int rem = n & 1023;
  int j = rem >> 2, g = rem & 3;
  const float* s = d ? sb : sf;
  dst[i] = (f16)s[(size_t)((g << 8) + j) * K + k];
}

__global__ void k_cvt_whh(const float* __restrict__ sf, const float* __restrict__ sb,
                          f16* __restrict__ dst) {
  int i = blockIdx.x * blockDim.x + threadIdx.x;
  if (i >= 524288) return;
  int d = i >> 18, rem = i & 262143;
  dst[i] = (f16)((d ? sb : sf)[rem]);
}

// ---------------- GEMM: C[m][n] = sum_k A[m][k]*B[n][k], C fp16 [M][2048] ----------------
// A fp16 rows (gathered via tokens if GATHER), B fp16 [2048][KD] row-major (B^T form).
// 128x128 tile, BK=64, 256 thr = 4 waves (2x2 of 64x64), mfma 16x16x32 f16.

template<int KD, bool GATHER>
__global__ __launch_bounds__(256)
void k_gemm(const f16* __restrict__ Abase, const f16* __restrict__ Bmat,
            const int* __restrict__ xtok, f16* __restrict__ C) {
  __shared__ __align__(16) char Al[128 * 64 * 2];
  __shared__ __align__(16) char Bl[128 * 64 * 2];
  __shared__ int toks[128];
  const int tid = threadIdx.x;
  const int lane = tid & 63, wave = tid >> 6;
  const int mt = blockIdx.x & 255;       // 256 M-tiles
  const int nt = blockIdx.x >> 8;        // 16 N-tiles
  const int Mb = mt * 128, Nb = nt * 128;

  if (GATHER) {
    if (tid < 128) {
      int m = Mb + tid;
      toks[tid] = xtok[(m & 63) * 512 + (m >> 6)];
    }
  }
  __syncthreads();

  const f16* asrc[4]; const f16* bsrc[4];
#pragma unroll
  for (int it = 0; it < 4; ++it) {
    int g = it * 256 + tid;
    int row = g >> 3, gc = g & 7;
    if (GATHER) asrc[it] = Abase + (size_t)toks[row] * KD + gc * 8;
    else        asrc[it] = Abase + (size_t)(Mb + row) * KD + gc * 8;
    bsrc[it] = Bmat + (size_t)(Nb + row) * KD + gc * 8;
  }

  floatx4 acc[4][4];
#pragma unroll
  for (int mi = 0; mi < 4; ++mi)
#pragma unroll
    for (int ni = 0; ni < 4; ++ni)
      acc[mi][ni] = (floatx4){0.f, 0.f, 0.f, 0.f};

  const int wr = wave >> 1, wc = wave & 1;

  for (int kt = 0; kt < KD / 64; ++kt) {
    __syncthreads();
#ifdef HAS_GLL
#pragma unroll
    for (int it = 0; it < 4; ++it) {
      __builtin_amdgcn_global_load_lds(
          (const __attribute__((address_space(1))) void*)(asrc[it]),
          (__attribute__((address_space(3))) void*)(Al + (it * 256 + wave * 64) * 16), 16, 0, 0);
      __builtin_amdgcn_global_load_lds(
          (const __attribute__((address_space(1))) void*)(bsrc[it]),
          (__attribute__((address_space(3))) void*)(Bl + (it * 256 + wave * 64) * 16), 16, 0, 0);
      asrc[it] += 64; bsrc[it] += 64;
    }
#else
    uint4 va[4], vb[4];
#pragma unroll
    for (int it = 0; it < 4; ++it) {
      va[it] = *(const uint4*)(asrc[it]);
      vb[it] = *(const uint4*)(bsrc[it]);
      asrc[it] += 64; bsrc[it] += 64;
    }
#pragma unroll
    for (int it = 0; it < 4; ++it) {
      *(uint4*)(Al + (it * 256 + wave * 64) * 16 + lane * 16) = va[it];
      *(uint4*)(Bl + (it * 256 + wave * 64) * 16 + lane * 16) = vb[it];
    }
#endif
    __syncthreads();

#pragma unroll
    for (int kk = 0; kk < 2; ++kk) {
      half8 av[4], bv[4];
#pragma unroll
      for (int mi = 0; mi < 4; ++mi) {
        int row = wr * 64 + mi * 16 + (lane & 15);
        av[mi] = *(const half8*)(Al + row * 128 + kk * 64 + (lane >> 4) * 16);
      }
#pragma unroll
      for (int ni = 0; ni < 4; ++ni) {
        int row = wc * 64 + ni * 16 + (lane & 15);
        bv[ni] = *(const half8*)(Bl + row * 128 + kk * 64 + (lane >> 4) * 16);
      }
#pragma unroll
      for (int mi = 0; mi < 4; ++mi)
#pragma unroll
        for (int ni = 0; ni < 4; ++ni)
          acc[mi][ni] = __builtin_amdgcn_mfma_f32_16x16x32_f16(av[mi], bv[ni], acc[mi][ni], 0, 0, 0);
    }
  }

  // epilogue: C layout col=lane&15, row=(lane>>4)*4+r
#pragma unroll
  for (int mi = 0; mi < 4; ++mi) {
#pragma unroll
    for (int ni = 0; ni < 4; ++ni) {
      floatx4 v = acc[mi][ni];
      int n = Nb + wc * 64 + ni * 16 + (lane & 15);
#pragma unroll
      for (int r = 0; r < 4; ++r) {
        int m = Mb + wr * 64 + mi * 16 + (lane >> 4) * 4 + r;
        C[(size_t)m * 2048 + n] = (f16)v[r];
      }
    }
  }
}

// ---------------- scan kernel ----------------
// 32 blocks x 256 thr. group gid=blockIdx&7 (dir=gid&1, batch-slice=gid>>1, 16 rows),
// member=blockIdx>>3 owns 64 hidden cols. Whh slice [256 gaterows][256 k] fp16 in LDS
// (rows packed [jgrp4][gate4][jl16], XOR-swizzle ^((row&7)<<4)). h [16][256] fp16 in LDS.
// One atomic-counter barrier per step; h exchanged via global ex buffer (parity dbuf).

template<int LAYER>
__global__ __launch_bounds__(256)
void k_scan(const f16* __restrict__ proj, const f16* __restrict__ whh,
            const float* __restrict__ bias_f, const float* __restrict__ bias_b,
            f16* __restrict__ h0out, float* __restrict__ finalh,
            f16* __restrict__ ex, unsigned* __restrict__ ctr) {
  extern __shared__ char lds[];
  char* Wl = lds;              // 128 KB
  char* Hl = lds + 131072;     // 8 KB
  const int tid = threadIdx.x, lane = tid & 63, wave = tid >> 6;
  const int gid = blockIdx.x & 7, member = blockIdx.x >> 3;
  const int d = gid & 1, bgrp = gid >> 1;
  const int bbase = bgrp * 16, c0 = member * 64;

  // load Whh slice into LDS (one row per thread, 512B each, swizzled)
  {
    int r = tid;
    int jgrp = r >> 6, gate = (r >> 4) & 3, jl = r & 15;
    int srcrow = gate * 256 + c0 + jgrp * 16 + jl;
    const f16* src = whh + (size_t)(d * 1024 + srcrow) * 256;
    int swz = (r & 7) << 4;
    char* dstrow = Wl + r * 512;
#pragma unroll 8
    for (int c = 0; c < 32; ++c)
      *(uint4*)(dstrow + ((c * 16) ^ swz)) = *(const uint4*)(src + c * 8);
  }
  // zero h
  for (int i = tid; i < 512; i += 256) ((uint4*)Hl)[i] = make_uint4(0, 0, 0, 0);

  const int rowsel = lane >> 4;            // 0..3
  const int jl = lane & 15;
  const int jglobal = c0 + wave * 16 + jl; // 0..255
  const float* bptr = d ? bias_b : bias_f;
  float bias[4];
#pragma unroll
  for (int g = 0; g < 4; ++g) bias[g] = bptr[g * 256 + jglobal];
  float cst[4] = {0.f, 0.f, 0.f, 0.f};

  // proj row m = tin*64 + bbase + rowsel*4 + r ; 4 gates packed at col d*1024 + jglobal*4
  uint2 pj[4];
  {
    int tin0 = d ? 511 : 0;
#pragma unroll
    for (int r = 0; r < 4; ++r) {
      size_t m = (size_t)tin0 * 64 + bbase + rowsel * 4 + r;
      pj[r] = *(const uint2*)(proj + m * 2048 + d * 1024 + (size_t)jglobal * 4);
    }
  }
  __syncthreads();

  const size_t exgbase = (size_t)gid * (2 * 16 * 256);

  for (int s = 0; s < 512; ++s) {
    const int tin = d ? (511 - s) : s;

    floatx4 acc[4];
#pragma unroll
    for (int r = 0; r < 4; ++r) {
      union { uint2 u; f16 h[4]; } cv; cv.u = pj[r];
      acc[0][r] = (float)cv.h[0] + bias[0];
      acc[1][r] = (float)cv.h[1] + bias[1];
      acc[2][r] = (float)cv.h[2] + bias[2];
      acc[3][r] = (float)cv.h[3] + bias[3];
    }
    // prefetch next step's proj
    if (s < 511) {
      int tin2 = d ? (510 - s) : (s + 1);
#pragma unroll
      for (int r = 0; r < 4; ++r) {
        size_t m = (size_t)tin2 * 64 + bbase + rowsel * 4 + r;
        pj[r] = *(const uint2*)(proj + m * 2048 + d * 1024 + (size_t)jglobal * 4);
      }
    }

    // g += h @ Wslice^T
    {
      const int b = lane & 15;
      const int asw = (b & 7) << 4;
      const int koffb = (lane >> 4) * 16;
#pragma unroll
      for (int kk = 0; kk < 8; ++kk) {
        half8 a = *(const half8*)(Hl + ((b * 512 + kk * 64 + koffb) ^ asw));
#pragma unroll
        for (int g = 0; g < 4; ++g) {
          int row = wave * 64 + g * 16 + (lane & 15);
          half8 bv = *(const half8*)(Wl + ((row * 512 + kk * 64 + koffb) ^ ((row & 7) << 4)));
          acc[g] = __builtin_amdgcn_mfma_f32_16x16x32_f16(a, bv, acc[g], 0, 0, 0);
        }
      }
    }

    // gates + state update + stores
    {
      f16* exw = ex + exgbase + (size_t)(s & 1) * (16 * 256);
#pragma unroll
      for (int r = 0; r < 4; ++r) {
        float iv = sigf(acc[0][r]);
        float fv = sigf(acc[1][r]);
        float gv = tanhf_(acc[2][r]);
        float ov = sigf(acc[3][r]);
        cst[r] = fv * cst[r] + iv * gv;
        float hv = ov * tanhf_(cst[r]);
        f16 hh = (f16)hv;
        int blocal = rowsel * 4 + r;
        int babs = bbase + blocal;
        exw[blocal * 256 + jglobal] = hh;
        if (LAYER == 0) {
          h0out[((size_t)tin * 64 + babs) * 512 + d * 256 + jglobal] = hh;
        } else {
          if (s == 511) finalh[(size_t)(d * 64 + babs) * 256 + jglobal] = hv;
        }
      }
    }

    __threadfence();
    __syncthreads();
    if (tid == 0) {
      unsigned* cp = ctr + gid * 512 + s;
      __hip_atomic_fetch_add(cp, 1u, __ATOMIC_RELEASE, __HIP_MEMORY_SCOPE_AGENT);
      unsigned v; int guard = 0;
      do {
        v = __hip_atomic_load(cp, __ATOMIC_RELAXED, __HIP_MEMORY_SCOPE_AGENT);
      } while (v < 4u && ++guard < (1 << 16));
      (void)__hip_atomic_load(cp, __ATOMIC_ACQUIRE, __HIP_MEMORY_SCOPE_AGENT);
    }
    __syncthreads();

    // copy ex[parity] -> Hl (swizzled)
    {
      const f16* src = ex + exgbase + (size_t)(s & 1) * (16 * 256);
#pragma unroll
      for (int jj = 0; jj < 2; ++jj) {
        int gg = tid * 2 + jj;
        int b = gg >> 5, gc = gg & 31;
        uint4 v = *(const uint4*)(src + b * 256 + gc * 8);
        *(uint4*)(Hl + ((b * 512 + gc * 16) ^ ((b & 7) << 4))) = v;
      }
    }
    __syncthreads();
  }
}

// ---------------- final linear ----------------
__global__ void k_final(const float* __restrict__ fh, const float* __restrict__ wlin,
                        const float* __restrict__ blin, float* __restrict__ out) {
  int tid = threadIdx.x;
  int b = tid >> 2, part = tid & 3;
  float sum = 0.f;
#pragma unroll 4
  for (int jj = 0; jj < 128; ++jj) {
    int j = part * 128 + jj;
    float lastv = (j < 256) ? fh[b * 256 + j] : fh[(64 + b) * 256 + (j - 256)];
    sum += lastv * wlin[j];
  }
  sum += __shfl_xor(sum, 1);
  sum += __shfl_xor(sum, 2);
  if (part == 0) out[b] = sum + blin[0];
}

// ---------------- host ----------------
extern "C" void kernel_launch(void* const* d_in, const int* in_sizes, int n_in,
                              void* d_out, int out_size, void* d_ws, size_t ws_size,
                              hipStream_t stream) {
  const int*   x     = (const int*)  d_in[0];
  const float* embed = (const float*)d_in[1];
  const float* wih0f = (const float*)d_in[2];
  const float* whh0f = (const float*)d_in[3];
  const float* b0f   = (const float*)d_in[4];
  const float* wih0b = (const float*)d_in[5];
  const float* whh0b = (const float*)d_in[6];
  const float* b0b   = (const float*)d_in[7];
  const float* wih1f = (const float*)d_in[8];
  const float* whh1f = (const float*)d_in[9];
  const float* b1f   = (const float*)d_in[10];
  const float* wih1b = (const float*)d_in[11];
  const float* whh1b = (const float*)d_in[12];
  const float* b1b   = (const float*)d_in[13];
  const float* wlin  = (const float*)d_in[14];
  const float* blin  = (const float*)d_in[15];

  char* ws = (char*)d_ws;
  size_t off = 0;
  auto alloc = [&](size_t bytes) {
    char* p = ws + off;
    off = (off + bytes + 511) & ~(size_t)511;
    return p;
  };
  f16* embed16 = (f16*)alloc((size_t)50000 * 256 * 2);
  f16* wih0_16 = (f16*)alloc((size_t)2048 * 256 * 2);
  f16* wih1_16 = (f16*)alloc((size_t)2048 * 512 * 2);
  f16* whh0_16 = (f16*)alloc((size_t)2 * 1024 * 256 * 2);
  f16* whh1_16 = (f16*)alloc((size_t)2 * 1024 * 256 * 2);
  f16* proj    = (f16*)alloc((size_t)32768 * 2048 * 2);
  f16* h0      = (f16*)alloc((size_t)32768 * 512 * 2);
  f16* ex      = (f16*)alloc((size_t)8 * 2 * 16 * 256 * 2);
  float* fh    = (float*)alloc((size_t)2 * 64 * 256 * 4);
  unsigned* ctr = (unsigned*)alloc((size_t)8 * 512 * 4);

  if (off > ws_size) {  // insufficient workspace: fail loudly with zeros
    hipMemsetAsync(d_out, 0, (size_t)out_size * 4, stream);
    return;
  }

  hipFuncSetAttribute(reinterpret_cast<const void*>(&k_scan<0>),
                      hipFuncAttributeMaxDynamicSharedMemorySize, 139264);
  hipFuncSetAttribute(reinterpret_cast<const void*>(&k_scan<1>),
                      hipFuncAttributeMaxDynamicSharedMemorySize, 139264);

  k_cvt_embed<<<(12800000 / 8 + 255) / 256, 256, 0, stream>>>(embed, embed16, 12800000 / 8);
  k_cvt_wih<<<(2048 * 256 + 255) / 256, 256, 0, stream>>>(wih0f, wih0b, wih0_16, 256, 8, 2048 * 256);
  k_cvt_wih<<<(2048 * 512 + 255) / 256, 256, 0, stream>>>(wih1f, wih1b, wih1_16, 512, 9, 2048 * 512);
  k_cvt_whh<<<(524288 + 255) / 256, 256, 0, stream>>>(whh0f, whh0b, whh0_16);
  k_cvt_whh<<<(524288 + 255) / 256, 256, 0, stream>>>(whh1f, whh1b, whh1_16);

  // layer 0 input projection: [32768,256] x [2048,256]^T -> proj
  k_gemm<256, true><<<4096, 256, 0, stream>>>(embed16, wih0_16, x, proj);
  hipMemsetAsync(ctr, 0, (size_t)8 * 512 * 4, stream);
  k_scan<0><<<32, 256, 139264, stream>>>(proj, whh0_16, b0f, b0b, h0, nullptr, ex, ctr);

  // layer 1 input projection: [32768,512] x [2048,512]^T -> proj (reuse)
  k_gemm<512, false><<<4096, 256, 0, stream>>>(h0, wih1_16, nullptr, proj);
  hipMemsetAsync(ctr, 0, (size_t)8 * 512 * 4, stream);
  k_scan<1><<<32, 256, 139264, stream>>>(proj, whh1_16, b1f, b1b, nullptr, fh, ex, ctr);

  k_final<<<1, 256, 0, stream>>>(fh, wlin, blin, (float*)d_out);
}

// Round 3
// 3071.384 us; speedup vs baseline: 1.8875x; 1.8875x over previous
//
#include <hip/hip_runtime.h>
#include <hip/hip_fp16.h>

// ReviewAnalyzeModel: 2-layer biLSTM, B=64 T=512 E=256 H=256, V=50000.
// prep(cvt fp16) -> GEMM proj0 -> scan0 -> GEMM proj1 -> scan1 -> final linear.
// Scan: 32 blocks; group gid=blockIdx&7 = (dir, batch-slice of 16); member=blockIdx>>3
// owns 64 hidden cols. Whh slice in VGPRs (128 regs/lane). h exchanged per step via a
// per-group global buffer. Sync = R1-proven protocol: tid0 release-agent atomic add
// (publishes prior stores via L2 writeback) + relaxed-agent spin + one acquire load
// (L2 inv), monotone per-group counter, two __syncthreads per step.

typedef _Float16 f16;
typedef _Float16 half8 __attribute__((ext_vector_type(8)));
typedef float floatx4 __attribute__((ext_vector_type(4)));

#if __has_builtin(__builtin_amdgcn_global_load_lds)
#define HAS_GLL 1
#endif

#if __has_builtin(__builtin_amdgcn_exp2f)
#define EXP2F __builtin_amdgcn_exp2f
#else
#define EXP2F exp2f
#endif
#if __has_builtin(__builtin_amdgcn_rcpf)
#define RCPF __builtin_amdgcn_rcpf
#else
#define RCPF(x) (1.0f/(x))
#endif

__device__ __forceinline__ float sigf(float x) {
  return RCPF(1.f + EXP2F(-1.4426950408889634f * x));
}
__device__ __forceinline__ float tanhf_(float x) {
  return 2.f * RCPF(1.f + EXP2F(-2.8853900817779268f * x)) - 1.f;
}

// ---------------- prep kernels ----------------

__global__ void k_cvt_embed(const float* __restrict__ src, f16* __restrict__ dst, int n8) {
  int i = blockIdx.x * blockDim.x + threadIdx.x;
  if (i >= n8) return;
  const float4* s = (const float4*)(src + (size_t)i * 8);
  float4 a = s[0], b = s[1];
  half8 h = { (f16)a.x,(f16)a.y,(f16)a.z,(f16)a.w,(f16)b.x,(f16)b.y,(f16)b.z,(f16)b.w };
  *(half8*)(dst + (size_t)i * 8) = h;
}

// dst[n'][k], n' = d*1024 + j*4 + gate ; src row (gate*256+j) of Wih_l?_{f,b}
__global__ void k_cvt_wih(const float* __restrict__ sf, const float* __restrict__ sb,
                          f16* __restrict__ dst, int K, int logK, int total) {
  int i = blockIdx.x * blockDim.x + threadIdx.x;
  if (i >= total) return;
  int k = i & (K - 1);
  int n = i >> logK;
  int d = n >> 10;
  int rem = n & 1023;
  int j = rem >> 2, g = rem & 3;
  const float* s = d ? sb : sf;
  dst[i] = (f16)s[(size_t)((g << 8) + j) * K + k];
}

__global__ void k_cvt_whh(const float* __restrict__ sf, const float* __restrict__ sb,
                          f16* __restrict__ dst) {
  int i = blockIdx.x * blockDim.x + threadIdx.x;
  if (i >= 524288) return;
  int d = i >> 18, rem = i & 262143;
  dst[i] = (f16)((d ? sb : sf)[rem]);
}

// ---------------- GEMM: C[m][n] = sum_k A[m][k]*B[n][k], C fp16 [M][2048] ----------------

template<int KD, bool GATHER>
__global__ __launch_bounds__(256)
void k_gemm(const f16* __restrict__ Abase, const f16* __restrict__ Bmat,
            const int* __restrict__ xtok, f16* __restrict__ C) {
  __shared__ __align__(16) char Al[128 * 64 * 2];
  __shared__ __align__(16) char Bl[128 * 64 * 2];
  __shared__ int toks[128];
  const int tid = threadIdx.x;
  const int lane = tid & 63, wave = tid >> 6;
  const int mt = blockIdx.x & 255;
  const int nt = blockIdx.x >> 8;
  const int Mb = mt * 128, Nb = nt * 128;

  if (GATHER) {
    if (tid < 128) {
      int m = Mb + tid;
      toks[tid] = xtok[(m & 63) * 512 + (m >> 6)];
    }
  }
  __syncthreads();

  const f16* asrc[4]; const f16* bsrc[4];
#pragma unroll
  for (int it = 0; it < 4; ++it) {
    int g = it * 256 + tid;
    int row = g >> 3, gc = g & 7;
    if (GATHER) asrc[it] = Abase + (size_t)toks[row] * KD + gc * 8;
    else        asrc[it] = Abase + (size_t)(Mb + row) * KD + gc * 8;
    bsrc[it] = Bmat + (size_t)(Nb + row) * KD + gc * 8;
  }

  floatx4 acc[4][4];
#pragma unroll
  for (int mi = 0; mi < 4; ++mi)
#pragma unroll
    for (int ni = 0; ni < 4; ++ni)
      acc[mi][ni] = (floatx4){0.f, 0.f, 0.f, 0.f};

  const int wr = wave >> 1, wc = wave & 1;

  for (int kt = 0; kt < KD / 64; ++kt) {
    __syncthreads();
#ifdef HAS_GLL
#pragma unroll
    for (int it = 0; it < 4; ++it) {
      __builtin_amdgcn_global_load_lds(
          (const __attribute__((address_space(1))) void*)(asrc[it]),
          (__attribute__((address_space(3))) void*)(Al + (it * 256 + wave * 64) * 16), 16, 0, 0);
      __builtin_amdgcn_global_load_lds(
          (const __attribute__((address_space(1))) void*)(bsrc[it]),
          (__attribute__((address_space(3))) void*)(Bl + (it * 256 + wave * 64) * 16), 16, 0, 0);
      asrc[it] += 64; bsrc[it] += 64;
    }
#else
    uint4 va[4], vb[4];
#pragma unroll
    for (int it = 0; it < 4; ++it) {
      va[it] = *(const uint4*)(asrc[it]);
      vb[it] = *(const uint4*)(bsrc[it]);
      asrc[it] += 64; bsrc[it] += 64;
    }
#pragma unroll
    for (int it = 0; it < 4; ++it) {
      *(uint4*)(Al + (it * 256 + wave * 64) * 16 + lane * 16) = va[it];
      *(uint4*)(Bl + (it * 256 + wave * 64) * 16 + lane * 16) = vb[it];
    }
#endif
    __syncthreads();

#pragma unroll
    for (int kk = 0; kk < 2; ++kk) {
      half8 av[4], bv[4];
#pragma unroll
      for (int mi = 0; mi < 4; ++mi) {
        int row = wr * 64 + mi * 16 + (lane & 15);
        av[mi] = *(const half8*)(Al + row * 128 + kk * 64 + (lane >> 4) * 16);
      }
#pragma unroll
      for (int ni = 0; ni < 4; ++ni) {
        int row = wc * 64 + ni * 16 + (lane & 15);
        bv[ni] = *(const half8*)(Bl + row * 128 + kk * 64 + (lane >> 4) * 16);
      }
#pragma unroll
      for (int mi = 0; mi < 4; ++mi)
#pragma unroll
        for (int ni = 0; ni < 4; ++ni)
          acc[mi][ni] = __builtin_amdgcn_mfma_f32_16x16x32_f16(av[mi], bv[ni], acc[mi][ni], 0, 0, 0);
    }
  }

#pragma unroll
  for (int mi = 0; mi < 4; ++mi) {
#pragma unroll
    for (int ni = 0; ni < 4; ++ni) {
      floatx4 v = acc[mi][ni];
      int n = Nb + wc * 64 + ni * 16 + (lane & 15);
#pragma unroll
      for (int r = 0; r < 4; ++r) {
        int m = Mb + wr * 64 + mi * 16 + (lane >> 4) * 4 + r;
        C[(size_t)m * 2048 + n] = (f16)v[r];
      }
    }
  }
}

// ---------------- scan kernel ----------------

template<int LAYER>
__global__ __launch_bounds__(256, 1)
void k_scan(const f16* __restrict__ proj, const f16* __restrict__ whh,
            const float* __restrict__ bias_f, const float* __restrict__ bias_b,
            f16* __restrict__ h0out, float* __restrict__ finalh,
            f16* __restrict__ ex, unsigned* __restrict__ ctr) {
  const int tid = threadIdx.x, lane = tid & 63, wave = tid >> 6;
  const int gid = blockIdx.x & 7;
  const int d = gid & 1, bgrp = gid >> 1;
  const int bbase = bgrp * 16, c0 = (blockIdx.x >> 3) * 64;
  const int rowsel = lane >> 4;             // 0..3 (k-subchunk / b-row group)
  const int jglobal = c0 + wave * 16 + (lane & 15);
  const int bA = lane & 15;                 // A-fragment b-row
  unsigned* cp = ctr + gid * 32;            // 128B stride per group

  // Whh slice into VGPRs: wreg[g][kk] = B-fragment (gate g, k-chunk kk)
  half8 wreg[4][8];
#pragma unroll
  for (int g = 0; g < 4; ++g)
#pragma unroll
    for (int kk = 0; kk < 8; ++kk)
      wreg[g][kk] = *(const half8*)(whh + ((size_t)(d * 1024 + g * 256 + jglobal)) * 256
                                    + kk * 32 + rowsel * 8);

  const float* bptr = d ? bias_b : bias_f;
  float bias[4];
#pragma unroll
  for (int g = 0; g < 4; ++g) bias[g] = bptr[g * 256 + jglobal];

  f16* exg = ex + (size_t)gid * 8192;
  // zero own 64-col slice of parity-1 (h(-1)=0): thread t -> b=t>>4, cols c0+(t&15)*4..+3
  {
    f16* z = exg + 4096 + (tid >> 4) * 256 + c0 + (tid & 15) * 4;
    *(uint2*)z = make_uint2(0, 0);
  }

  float cst[4] = {0.f, 0.f, 0.f, 0.f};

  // prologue: proj row for step 0
  uint2 pj[4];
  {
    int t0 = d ? 511 : 0;
#pragma unroll
    for (int r = 0; r < 4; ++r)
      pj[r] = *(const uint2*)(proj + ((size_t)t0 * 64 + bbase + rowsel * 4 + r) * 2048
                              + d * 1024 + (size_t)jglobal * 4);
  }

  for (int s = 0; s < 512; ++s) {
    // barrier 1: drain this block's stores (zero-fill at s=0, step s-1 stores after)
    __syncthreads();
    if (tid == 0) {
      // release-add publishes this block's prior stores (L2 writeback),
      // then wait for all 4 blocks of the group to publish step s-1.
      __hip_atomic_fetch_add(cp, 1u, __ATOMIC_RELEASE, __HIP_MEMORY_SCOPE_AGENT);
      unsigned target = 4u * (unsigned)(s + 1);
      unsigned v; int gd = 0;
      do {
        v = __hip_atomic_load(cp, __ATOMIC_RELAXED, __HIP_MEMORY_SCOPE_AGENT);
      } while (v < target && ++gd < (1 << 18));
      (void)__hip_atomic_load(cp, __ATOMIC_ACQUIRE, __HIP_MEMORY_SCOPE_AGENT);
    }
    __syncthreads();

    // h(s-1) -> A-fragments (plain loads; caches were invalidated by the acquire)
    const f16* exr = exg + ((s & 1) ^ 1) * 4096 + bA * 256 + rowsel * 8;
    uint4 a4[8];
#pragma unroll
    for (int kk = 0; kk < 8; ++kk)
      a4[kk] = *(const uint4*)(exr + kk * 32);

    // prefetch next step's proj into registers (hidden under MFMA+gates)
    uint2 pjn[4];
    {
      int sn = (s < 511) ? s + 1 : 511;
      int tn = d ? 511 - sn : sn;
#pragma unroll
      for (int r = 0; r < 4; ++r)
        pjn[r] = *(const uint2*)(proj + ((size_t)tn * 64 + bbase + rowsel * 4 + r) * 2048
                                 + d * 1024 + (size_t)jglobal * 4);
    }

    floatx4 acc[4];
#pragma unroll
    for (int r = 0; r < 4; ++r) {
      union { uint2 u; f16 h[4]; } cv; cv.u = pj[r];
      acc[0][r] = (float)cv.h[0] + bias[0];
      acc[1][r] = (float)cv.h[1] + bias[1];
      acc[2][r] = (float)cv.h[2] + bias[2];
      acc[3][r] = (float)cv.h[3] + bias[3];
    }
#pragma unroll
    for (int kk = 0; kk < 8; ++kk) {
      half8 av = __builtin_bit_cast(half8, a4[kk]);
#pragma unroll
      for (int g = 0; g < 4; ++g)
        acc[g] = __builtin_amdgcn_mfma_f32_16x16x32_f16(av, wreg[g][kk], acc[g], 0, 0, 0);
    }

    const int tin = d ? 511 - s : s;
    f16* exw = exg + (s & 1) * 4096;
#pragma unroll
    for (int r = 0; r < 4; ++r) {
      float iv = sigf(acc[0][r]);
      float fv = sigf(acc[1][r]);
      float gv = tanhf_(acc[2][r]);
      float ov = sigf(acc[3][r]);
      cst[r] = fv * cst[r] + iv * gv;
      float hv = ov * tanhf_(cst[r]);
      f16 hh = (f16)hv;
      int blocal = rowsel * 4 + r;
      exw[blocal * 256 + jglobal] = hh;
      if (LAYER == 0) {
        h0out[((size_t)tin * 64 + bbase + blocal) * 512 + d * 256 + jglobal] = hh;
      } else if (s == 511) {
        finalh[(size_t)(d * 64 + bbase + blocal) * 256 + jglobal] = hv;
      }
    }
#pragma unroll
    for (int r = 0; r < 4; ++r) pj[r] = pjn[r];
  }
}

// ---------------- final linear ----------------
__global__ void k_final(const float* __restrict__ fh, const float* __restrict__ wlin,
                        const float* __restrict__ blin, float* __restrict__ out) {
  int tid = threadIdx.x;
  int b = tid >> 2, part = tid & 3;
  float sum = 0.f;
#pragma unroll 4
  for (int jj = 0; jj < 128; ++jj) {
    int j = part * 128 + jj;
    float lastv = (j < 256) ? fh[b * 256 + j] : fh[(64 + b) * 256 + (j - 256)];
    sum += lastv * wlin[j];
  }
  sum += __shfl_xor(sum, 1);
  sum += __shfl_xor(sum, 2);
  if (part == 0) out[b] = sum + blin[0];
}

// ---------------- host ----------------
extern "C" void kernel_launch(void* const* d_in, const int* in_sizes, int n_in,
                              void* d_out, int out_size, void* d_ws, size_t ws_size,
                              hipStream_t stream) {
  const int*   x     = (const int*)  d_in[0];
  const float* embed = (const float*)d_in[1];
  const float* wih0f = (const float*)d_in[2];
  const float* whh0f = (const float*)d_in[3];
  const float* b0f   = (const float*)d_in[4];
  const float* wih0b = (const float*)d_in[5];
  const float* whh0b = (const float*)d_in[6];
  const float* b0b   = (const float*)d_in[7];
  const float* wih1f = (const float*)d_in[8];
  const float* whh1f = (const float*)d_in[9];
  const float* b1f   = (const float*)d_in[10];
  const float* wih1b = (const float*)d_in[11];
  const float* whh1b = (const float*)d_in[12];
  const float* b1b   = (const float*)d_in[13];
  const float* wlin  = (const float*)d_in[14];
  const float* blin  = (const float*)d_in[15];

  char* ws = (char*)d_ws;
  size_t off = 0;
  auto alloc = [&](size_t bytes) {
    char* p = ws + off;
    off = (off + bytes + 511) & ~(size_t)511;
    return p;
  };
  f16* embed16 = (f16*)alloc((size_t)50000 * 256 * 2);
  f16* wih0_16 = (f16*)alloc((size_t)2048 * 256 * 2);
  f16* wih1_16 = (f16*)alloc((size_t)2048 * 512 * 2);
  f16* whh0_16 = (f16*)alloc((size_t)2 * 1024 * 256 * 2);
  f16* whh1_16 = (f16*)alloc((size_t)2 * 1024 * 256 * 2);
  f16* proj    = (f16*)alloc((size_t)32768 * 2048 * 2);
  f16* h0      = (f16*)alloc((size_t)32768 * 512 * 2);
  f16* ex      = (f16*)alloc((size_t)8 * 2 * 16 * 256 * 2);
  float* fh    = (float*)alloc((size_t)2 * 64 * 256 * 4);
  unsigned* ctr = (unsigned*)alloc((size_t)8 * 32 * 4);

  if (off > ws_size) {
    hipMemsetAsync(d_out, 0, (size_t)out_size * 4, stream);
    return;
  }

  k_cvt_embed<<<(12800000 / 8 + 255) / 256, 256, 0, stream>>>(embed, embed16, 12800000 / 8);
  k_cvt_wih<<<(2048 * 256 + 255) / 256, 256, 0, stream>>>(wih0f, wih0b, wih0_16, 256, 8, 2048 * 256);
  k_cvt_wih<<<(2048 * 512 + 255) / 256, 256, 0, stream>>>(wih1f, wih1b, wih1_16, 512, 9, 2048 * 512);
  k_cvt_whh<<<(524288 + 255) / 256, 256, 0, stream>>>(whh0f, whh0b, whh0_16);
  k_cvt_whh<<<(524288 + 255) / 256, 256, 0, stream>>>(whh1f, whh1b, whh1_16);

  // layer 0 input projection: [32768,256] x [2048,256]^T -> proj
  k_gemm<256, true><<<4096, 256, 0, stream>>>(embed16, wih0_16, x, proj);
  hipMemsetAsync(ctr, 0, (size_t)8 * 32 * 4, stream);
  k_scan<0><<<32, 256, 0, stream>>>(proj, whh0_16, b0f, b0b, h0, nullptr, ex, ctr);

  // layer 1 input projection: [32768,512] x [2048,512]^T -> proj (reuse)
  k_gemm<512, false><<<4096, 256, 0, stream>>>(h0, wih1_16, nullptr, proj);
  hipMemsetAsync(ctr, 0, (size_t)8 * 32 * 4, stream);
  k_scan<1><<<32, 256, 0, stream>>>(proj, whh1_16, b1f, b1b, nullptr, fh, ex, ctr);

  k_final<<<1, 256, 0, stream>>>(fh, wlin, blin, (float*)d_out);
}